// Round 14
// baseline (186.249 us; speedup 1.0000x reference)
//
#include <hip/hip_runtime.h>
#include <hip/hip_bf16.h>

#define N_ROWS 8192
#define D_DIM  1024
#define M_EXP  128
#define B_DIM  64
#define K_SEL  8

// ---- output layout (floats), in reference return order ----
#define HS_OFF  0                               // h_sparse: N*K*B
#define IDX_OFF (N_ROWS * K_SEL * B_DIM)        // topk_idxs as float: N*K
#define SC_OFF  (IDX_OFF + N_ROWS * K_SEL)      // 5 scalars

// ---- FAST-path workspace layout (bytes) ----
// epart: [t][s] 128x64 f32 (atomics spread); cnt: stride-64 ints
#define F_EPART   0                             // 32 KB
#define F_CNT     32768                         // 32 KB (spread x64)
#define F_ZERO    65536                         // bytes zeroed by zero_kernel
#define F_LISTS   65536                         // 128*8192 int (4 MB)
#define F_HSB     4259840                       // h_sparse bf16: 8 MB
#define F_VB      (F_HSB + 8388608)             // V bf16: 16 MB
#define F_Y       (F_VB + 16777216)             // 128 MB
#define F_CAPT    (F_Y + 134217728)             // 8192 f32 per-block capt partials
#define F_RECON   (F_CAPT + 32768)              // 4096 f32
#define F_UNCAP   (F_RECON + 16384)             // 4096 f32
#define F_NEED    (F_UNCAP + 16384)

// ---- FALLBACK workspace layout (bytes) ----
#define WS_XHAT   0
#define WS_EPART  33554432
#define WS_CNT    (33554432 + 32768)
#define WS_SC     (WS_CNT + 512)
#define WS_ZERO_BYTES (WS_SC + 16)
#define WS_LISTS  WS_ZERO_BYTES

typedef __attribute__((ext_vector_type(8))) short bhalf8;
typedef __attribute__((ext_vector_type(4))) float f32x4;

__device__ __forceinline__ unsigned bfbits(float f) {
  unsigned u = __float_as_uint(f);
  return (u + 0x7FFFu + ((u >> 16) & 1u)) >> 16;   // RNE f32->bf16 (finite inputs)
}

// ============================================================
// zero_kernel: zero epart+cnt (must precede topk's atomics)
// ============================================================
__global__ __launch_bounds__(256) void zero_kernel(float* __restrict__ ws) {
  int i = blockIdx.x * 256 + threadIdx.x;
  if (i < (F_ZERO / 4)) ws[i] = 0.f;
}

// ============================================================
// Kernel A (fused): blocks 0..8191 = topk, ONE row per block
// (32 KB LDS -> 4 blocks/CU); blocks 8192..12287 = V f32->bf16.
// Energy: 2 threads per expert; thread-half 0 sums even float4s
// (left subtree (r0+r1)+(r2+r3)), half 1 odd float4s (right
// subtree) -> final = left+right, bit-identical to numpy pairwise.
// ============================================================
__global__ __launch_bounds__(256) void topk_kernel(
    const float* __restrict__ h, const float* __restrict__ V,
    float* __restrict__ out,
    float* __restrict__ epart, int* __restrict__ cnt,
    int* __restrict__ lists, float* __restrict__ capt_part,
    uint2* __restrict__ hsb, uint4* __restrict__ Vb)
{
#pragma clang fp contract(off)
  const int t = threadIdx.x;

  if (blockIdx.x >= 8192) {
    // ---- V convert: 8 floats per thread ----
    const int k = (blockIdx.x - 8192) * 256 + t;
    const float4* vp = (const float4*)V + (size_t)k * 2;
    float4 a = vp[0], c = vp[1];
    uint4 u;
    u.x = bfbits(a.x) | (bfbits(a.y) << 16);
    u.y = bfbits(a.z) | (bfbits(a.w) << 16);
    u.z = bfbits(c.x) | (bfbits(c.y) << 16);
    u.w = bfbits(c.z) | (bfbits(c.w) << 16);
    Vb[k] = u;
    return;
  }

  const int n = blockIdx.x;

  __shared__ float4 buf[2048];      // 32 KB: one row, swizzled
  __shared__ float  sEh[2][M_EXP];
  __shared__ float  sE[M_EXP];
  __shared__ int    sIdx[K_SEL];

  // ---- stage row: coalesced reads, swizzled LDS writes ----
  const float4* hrow = (const float4*)h + (size_t)n * 2048;
  {
    float4 v[8];
#pragma unroll
    for (int f = 0; f < 8; ++f) v[f] = hrow[f * 256 + t];
#pragma unroll
    for (int f = 0; f < 8; ++f) {
      const int G = f * 256 + t;
      const int e = G >> 4, c = G & 15;
      buf[e * 16 + (c ^ (e & 7))] = v[f];
    }
  }
  __syncthreads();

  // ---- energy: 2 threads/expert, exact pairwise subtrees ----
  {
    const int e = t & 127, half = t >> 7;
    const int base = e * 16, sw = e & 7;
    float r0 = 0.f, r1 = 0.f, r2 = 0.f, r3 = 0.f;
#pragma unroll
    for (int cc = 0; cc < 16; cc += 2) {
      const int c = cc + half;            // half0: even c; half1: odd c
      float4 a = buf[base + (c ^ sw)];
      r0 += a.x * a.x;  r1 += a.y * a.y;  r2 += a.z * a.z;  r3 += a.w * a.w;
    }
    sEh[half][e] = (r0 + r1) + (r2 + r3);
  }
  __syncthreads();

  if (t < 128) {
    const float s = sEh[0][t] + sEh[1][t];   // = ((r0+r1)+(r2+r3))+((r4+r5)+(r6+r7))
    sE[t] = s;
    // epart [t][s]: block's 128 atomics land on 128 distinct cache lines
    atomicAdd(&epart[t * 64 + (blockIdx.x & 63)], s);
  }
  __syncthreads();

  // ---- top-8: wave 0 ----
  if (t < 64) {
    const int lane = t;
    float ea = sE[lane];
    float eb = sE[lane + 64];
    float capt = 0.f;
#pragma unroll
    for (int j = 0; j < K_SEL; ++j) {
      float v; int idx;
      if (eb > ea) { v = eb; idx = lane + 64; } else { v = ea; idx = lane; }
#pragma unroll
      for (int off = 32; off >= 1; off >>= 1) {
        float ov = __shfl_xor(v, off);
        int   oi = __shfl_xor(idx, off);
        if (ov > v || (ov == v && oi < idx)) { v = ov; idx = oi; }
      }
      if (lane == 0) sIdx[j] = idx;
      if (idx == lane)      ea = -3.402823466e38f;
      if (idx == lane + 64) eb = -3.402823466e38f;
      capt += v;
    }
    if (lane == 0) capt_part[n] = capt;
  }
  __syncthreads();

  // ---- idx output + expert list append (stride-64 cnt) ----
  if (t < K_SEL) {
    const int ii = sIdx[t];
    out[IDX_OFF + n * K_SEL + t] = (float)ii;
    int pos = atomicAdd(&cnt[ii * 64], 1);
    lists[ii * N_ROWS + pos] = (n << 3) | t;
  }

  // ---- gather h_sparse from LDS: f32 to out + bf16 to hsb ----
  if (t < 128) {
    const int j = t >> 4, c4 = t & 15;
    const int src = sIdx[j];
    float4 v = buf[src * 16 + (c4 ^ (src & 7))];
    ((float4*)out)[((size_t)n * K_SEL + j) * 16 + c4] = v;
    uint2 u;
    u.x = bfbits(v.x) | (bfbits(v.y) << 16);
    u.y = bfbits(v.z) | (bfbits(v.w) << 16);
    hsb[((size_t)n * K_SEL + j) * 16 + c4] = u;
  }
}

// ============================================================
// FAST Kernel B1 (MFMA v3): swapped operands, z=2 chunks.
// grid (8 d-tiles, 128 experts, 2 chunks) x 256.
// ============================================================
__global__ __launch_bounds__(256, 2) void b1_kernel(
    const uint4* __restrict__ Vb, const uint4* __restrict__ hsb,
    const int* __restrict__ cnt, const int* __restrict__ lists,
    uint4* __restrict__ y)
{
  const int t  = threadIdx.x;
  const int d0 = blockIdx.x * 128;
  const int ex = blockIdx.y;
  const int c  = cnt[ex * 64];
  if ((int)(blockIdx.z * 128) >= c) return;

  __shared__ uint4 mem[2048];     // Vl (prologue) / Hl; Ol aliases all
  __shared__ int   qbuf[128];

  const int w = t >> 6, l = t & 63;
  const int l15 = l & 15, l4 = l >> 4;

  // ---- stage V tile once (bf16, swizzled): 2 threads / d-row ----
  {
    const int d = t >> 1, half = t & 1;
    const uint4* vp = Vb + (size_t)(d0 + d) * 1024 + ex * 8 + half * 4;
#pragma unroll
    for (int jj = 0; jj < 4; ++jj) {
      const int cI = half * 4 + jj;
      mem[d * 8 + (cI ^ (d & 7))] = vp[jj];
    }
  }
  __syncthreads();

  // ---- V fragments (A operand), reg-cached; Vl LDS dead afterwards ----
  bhalf8 vf[8][2];
#pragma unroll
  for (int dt = 0; dt < 8; ++dt)
#pragma unroll
    for (int kh = 0; kh < 2; ++kh) {
      const int d = dt * 16 + l15;
      const int kc = kh * 4 + l4;
      vf[dt][kh] = *(const bhalf8*)&mem[d * 8 + (kc ^ (d & 7))];
    }
  __syncthreads();

  for (int ybase = blockIdx.z * 128; ybase < c; ybase += 256) {
    const int rows = min(128, c - ybase);

    // ---- stage h rows (bf16, swizzled) into mem[1024..2047] ----
    {
      const int r = t >> 1, half = t & 1;
      if (r < rows) {
        const int q = lists[ex * N_ROWS + ybase + r];
        if (half == 0) qbuf[r] = q;
        const uint4* hp = hsb + (size_t)q * 8 + half * 4;
#pragma unroll
        for (int jj = 0; jj < 4; ++jj) {
          const int cI = half * 4 + jj;
          mem[1024 + r * 8 + (cI ^ (r & 7))] = hp[jj];
        }
      }
    }
    __syncthreads();

    // ---- h fragments (B operand) ----
    bhalf8 hf[2][2];
#pragma unroll
    for (int rt = 0; rt < 2; ++rt)
#pragma unroll
      for (int kh = 0; kh < 2; ++kh) {
        const int r = w * 32 + rt * 16 + l15;
        const int kc = kh * 4 + l4;
        hf[rt][kh] = *(const bhalf8*)&mem[1024 + r * 8 + (kc ^ (r & 7))];
      }

    f32x4 acc[2][8];
#pragma unroll
    for (int rt = 0; rt < 2; ++rt)
#pragma unroll
      for (int dt = 0; dt < 8; ++dt)
        acc[rt][dt] = (f32x4){0.f, 0.f, 0.f, 0.f};

#pragma unroll
    for (int kh = 0; kh < 2; ++kh)
#pragma unroll
      for (int rt = 0; rt < 2; ++rt)
#pragma unroll
        for (int dt = 0; dt < 8; ++dt)
          acc[rt][dt] = __builtin_amdgcn_mfma_f32_16x16x32_bf16(
              vf[dt][kh], hf[rt][kh], acc[rt][dt], 0, 0, 0);

    __syncthreads();   // all Hl reads done; Ol may overwrite mem

    // ---- D -> Ol: lane holds 4 consecutive d-cols of one local row ----
    {
      uint2* Ol2 = (uint2*)mem;
#pragma unroll
      for (int rt = 0; rt < 2; ++rt) {
        const int j2 = w * 32 + rt * 16 + l15;
#pragma unroll
        for (int dt = 0; dt < 8; ++dt) {
          const f32x4 a = acc[rt][dt];
          uint2 u;
          u.x = bfbits(a[0]) | (bfbits(a[1]) << 16);
          u.y = bfbits(a[2]) | (bfbits(a[3]) << 16);
          const int ch = dt * 2 + (l4 >> 1);          // 16B chunk = col/8
          Ol2[j2 * 32 + ((ch ^ (j2 & 7)) << 1) + (l4 & 1)] = u;
        }
      }
    }
    __syncthreads();

    // ---- coalesced y stores: 16 threads/row ----
    {
      const int rloc = t >> 4, cI = t & 15;
#pragma unroll
      for (int p = 0; p < 8; ++p) {
        const int row = p * 16 + rloc;
        if (row < rows)
          y[(size_t)qbuf[row] * 128 + blockIdx.x * 16 + cI] =
              mem[row * 16 + (cI ^ (row & 7))];
      }
    }
    __syncthreads();   // before next iteration restages Hl over Ol
  }
}

// ============================================================
// FAST Kernel B2: fold y over j -> x_hat in regs -> recon/uncap.
// ============================================================
__global__ __launch_bounds__(256) void b2_kernel(
    const float* __restrict__ x, const uint4* __restrict__ y,
    float* __restrict__ recon_part, float* __restrict__ uncap_part)
{
  const int tid = blockIdx.x * 256 + threadIdx.x;
  const int n = tid >> 7, dc = tid & 127;

  float xh[8] = {0.f,0.f,0.f,0.f,0.f,0.f,0.f,0.f};
  const uint4* yp = y + (size_t)n * (8 * 128) + dc;
#pragma unroll
  for (int j = 0; j < 8; ++j) {
    uint4 u = yp[(size_t)j * 128];
    xh[0] += __uint_as_float(u.x << 16);
    xh[1] += __uint_as_float(u.x & 0xFFFF0000u);
    xh[2] += __uint_as_float(u.y << 16);
    xh[3] += __uint_as_float(u.y & 0xFFFF0000u);
    xh[4] += __uint_as_float(u.z << 16);
    xh[5] += __uint_as_float(u.z & 0xFFFF0000u);
    xh[6] += __uint_as_float(u.w << 16);
    xh[7] += __uint_as_float(u.w & 0xFFFF0000u);
  }
  const float4* xp = (const float4*)(x + (size_t)n * D_DIM + dc * 8);
  float4 a0 = xp[0], a1 = xp[1];
  float xv[8] = {a0.x, a0.y, a0.z, a0.w, a1.x, a1.y, a1.z, a1.w};

  float recon = 0.f, uncap = 0.f;
#pragma unroll
  for (int i = 0; i < 8; ++i) {
    recon += xh[i] * xh[i];
    float dd = xv[i] - xh[i];
    uncap += dd * dd;
  }

#pragma unroll
  for (int off = 32; off >= 1; off >>= 1) {
    recon += __shfl_down(recon, off);
    uncap += __shfl_down(uncap, off);
  }
  __shared__ float sR[4], sU[4];
  int wid = threadIdx.x >> 6, lane = threadIdx.x & 63;
  if (lane == 0) { sR[wid] = recon; sU[wid] = uncap; }
  __syncthreads();
  if (threadIdx.x == 0) {
    recon_part[blockIdx.x] = sR[0] + sR[1] + sR[2] + sR[3];
    uncap_part[blockIdx.x] = sU[0] + sU[1] + sU[2] + sU[3];
  }
}

// ============================================================
// FAST finalize: sum partials + entropy + scalars (epart [t][s])
// ============================================================
__global__ __launch_bounds__(128) void finalize_kernel(
    const float* __restrict__ epart, const float* __restrict__ capt_part,
    const float* __restrict__ recon_part, const float* __restrict__ uncap_part,
    float* __restrict__ out)
{
  const int t = threadIdx.x;
  __shared__ float sAvg[M_EXP];
  __shared__ float red[3][2];

  float s = 0.f;
  for (int c2 = 0; c2 < 64; ++c2) s += epart[t * 64 + c2];
  sAvg[t] = s / (float)N_ROWS;

  float pc = 0.f, pr = 0.f, pu = 0.f;
  for (int i = t; i < 8192; i += 128) pc += capt_part[i];
  for (int i = t; i < 4096; i += 128) {
    pr += recon_part[i];
    pu += uncap_part[i];
  }
#pragma unroll
  for (int off = 32; off >= 1; off >>= 1) {
    pc += __shfl_down(pc, off);
    pr += __shfl_down(pr, off);
    pu += __shfl_down(pu, off);
  }
  const int wid = t >> 6, lane = t & 63;
  if (lane == 0) { red[0][wid] = pc; red[1][wid] = pr; red[2][wid] = pu; }
  __syncthreads();

  if (t == 0) {
    float denom = 0.f;
    for (int i = 0; i < M_EXP; ++i) denom += sAvg[i];
    if (denom < 1e-8f) denom = 1e-8f;
    float ent = 0.f;
    for (int i = 0; i < M_EXP; ++i) {
      float p = sAvg[i] / denom;
      if (p < 1e-8f) p = 1e-8f;
      ent += p * logf(p);
    }
    float bal   = -ent / logf(128.0f);
    float capt  = (red[0][0] + red[0][1]) / (float)N_ROWS;
    float recon = (red[1][0] + red[1][1]) / (float)N_ROWS;
    float uncap = (red[2][0] + red[2][1]) / (float)N_ROWS;
    out[SC_OFF + 0] = capt;
    out[SC_OFF + 1] = recon;
    out[SC_OFF + 2] = uncap;
    out[SC_OFF + 3] = bal;
    out[SC_OFF + 4] = uncap + 0.5f * (1.0f - bal);
  }
}

// ============================================================
// FALLBACK kernels (only used if ws too small)
// ============================================================
__global__ __launch_bounds__(128) void topk_fb_kernel(
    const float* __restrict__ h, float* __restrict__ out,
    float* __restrict__ epart, int* __restrict__ cnt,
    int* __restrict__ lists, float* __restrict__ sc)
{
#pragma clang fp contract(off)
  const int n = blockIdx.x;
  const int t = threadIdx.x;
  __shared__ float sE[M_EXP];
  __shared__ int   sIdx[K_SEL];
  const float4* hp = (const float4*)(h + (size_t)n * (M_EXP * B_DIM) + t * B_DIM);
  float r0=0.f,r1=0.f,r2=0.f,r3=0.f,r4=0.f,r5=0.f,r6=0.f,r7=0.f;
#pragma unroll
  for (int f = 0; f < 16; f += 2) {
    float4 a = hp[f];
    float4 b = hp[f + 1];
    r0 += a.x * a.x;  r1 += a.y * a.y;  r2 += a.z * a.z;  r3 += a.w * a.w;
    r4 += b.x * b.x;  r5 += b.y * b.y;  r6 += b.z * b.z;  r7 += b.w * b.w;
  }
  const float e = ((r0 + r1) + (r2 + r3)) + ((r4 + r5) + (r6 + r7));
  sE[t] = e;
  atomicAdd(&epart[(n & 63) * M_EXP + t], e);
  __syncthreads();
  if (t < 64) {
    float ea = sE[t], eb = sE[t + 64], capt = 0.f;
#pragma unroll
    for (int j = 0; j < K_SEL; ++j) {
      float v; int idx;
      if (eb > ea) { v = eb; idx = t + 64; } else { v = ea; idx = t; }
#pragma unroll
      for (int off = 32; off >= 1; off >>= 1) {
        float ov = __shfl_xor(v, off);
        int   oi = __shfl_xor(idx, off);
        if (ov > v || (ov == v && oi < idx)) { v = ov; idx = oi; }
      }
      if (t == 0) sIdx[j] = idx;
      if (idx == t)      ea = -3.402823466e38f;
      if (idx == t + 64) eb = -3.402823466e38f;
      capt += v;
    }
    if (t == 0) atomicAdd(&sc[0], capt);
  }
  __syncthreads();
  if (t < K_SEL) {
    int ii = sIdx[t];
    out[IDX_OFF + n * K_SEL + t] = (float)ii;
    int pos = atomicAdd(&cnt[ii], 1);
    lists[ii * N_ROWS + pos] = (n << 3) | t;
  }
  {
    int j = t >> 4, c4 = t & 15;
    int src = sIdx[j];
    const float4* gp = (const float4*)(h + (size_t)n * (M_EXP * B_DIM) + src * B_DIM);
    float4 v = gp[c4];
    ((float4*)(out + (size_t)n * (K_SEL * B_DIM) + j * B_DIM))[c4] = v;
  }
}

__global__ __launch_bounds__(128) void xhat_kernel(
    const float* __restrict__ V, const float* __restrict__ out,
    const int* __restrict__ cnt, const int* __restrict__ lists,
    float* __restrict__ xhat)
{
  const int t  = threadIdx.x;
  const int d0 = blockIdx.x * 128;
  const int ex = blockIdx.y;
  const int ybase = blockIdx.z * 512;
  const int c = cnt[ex];
  if (ybase >= c) return;
  const int rowsChunk = min(512, c - ybase);
  __shared__ float Vt[64 * 132];
  __shared__ float hvT[64 * 68];
  __shared__ int   nbuf[64];
  {
    const float4* vp = (const float4*)(V + (size_t)(d0 + t) * (M_EXP * B_DIM) + ex * B_DIM);
    const int colt = t + ((t >> 6) << 2);
#pragma unroll
    for (int f = 0; f < 16; ++f) {
      float4 vv = vp[f];
      int b = f * 4;
      Vt[(b + 0) * 132 + colt] = vv.x;
      Vt[(b + 1) * 132 + colt] = vv.y;
      Vt[(b + 2) * 132 + colt] = vv.z;
      Vt[(b + 3) * 132 + colt] = vv.w;
    }
  }
  const int rg = t >> 4, dg = t & 15;
  const int hvBase = rg * 8;
  const int vBase  = dg * 8 + ((dg >> 3) << 2);
  for (int it = 0; it * 64 < rowsChunk; ++it) {
    const int rows = min(64, rowsChunk - it * 64);
    {
      const int r = t >> 1, half = t & 1;
      if (r < rows) {
        int q = lists[ex * N_ROWS + ybase + it * 64 + r];
        int nn = q >> 3, jj = q & 7;
        if (half == 0) nbuf[r] = nn;
        const float4* hp = (const float4*)(out + ((size_t)nn * K_SEL + jj) * B_DIM + half * 32);
#pragma unroll
        for (int f = 0; f < 8; ++f) {
          float4 hv = hp[f];
          int b = half * 32 + f * 4;
          hvT[(b + 0) * 68 + r] = hv.x;
          hvT[(b + 1) * 68 + r] = hv.y;
          hvT[(b + 2) * 68 + r] = hv.z;
          hvT[(b + 3) * 68 + r] = hv.w;
        }
      } else {
        if (half == 0) nbuf[r] = 0;
#pragma unroll
        for (int f = 0; f < 8; ++f) {
          int b = half * 32 + f * 4;
          hvT[(b + 0) * 68 + r] = 0.f;
          hvT[(b + 1) * 68 + r] = 0.f;
          hvT[(b + 2) * 68 + r] = 0.f;
          hvT[(b + 3) * 68 + r] = 0.f;
        }
      }
    }
    __syncthreads();
    float acc[8][8];
#pragma unroll
    for (int a = 0; a < 8; ++a)
#pragma unroll
      for (int d = 0; d < 8; ++d) acc[a][d] = 0.f;
#pragma unroll 4
    for (int b = 0; b < 64; ++b) {
      float4 h0 = *(const float4*)&hvT[b * 68 + hvBase];
      float4 h1 = *(const float4*)&hvT[b * 68 + hvBase + 4];
      float4 v0 = *(const float4*)&Vt[b * 132 + vBase];
      float4 v1 = *(const float4*)&Vt[b * 132 + vBase + 4];
      float hv[8] = {h0.x, h0.y, h0.z, h0.w, h1.x, h1.y, h1.z, h1.w};
      float vv[8] = {v0.x, v0.y, v0.z, v0.w, v1.x, v1.y, v1.z, v1.w};
#pragma unroll
      for (int a = 0; a < 8; ++a)
#pragma unroll
        for (int d = 0; d < 8; ++d)
          acc[a][d] = fmaf(hv[a], vv[d], acc[a][d]);
    }
#pragma unroll
    for (int a = 0; a < 8; ++a) {
      int r2 = rg * 8 + a;
      if (r2 < rows) {
        float* xp = xhat + (size_t)nbuf[r2] * D_DIM + d0 + dg * 8;
#pragma unroll
        for (int d = 0; d < 8; ++d) atomicAdd(xp + d, acc[a][d]);
      }
    }
    __syncthreads();
  }
}

__global__ __launch_bounds__(256) void reduce_kernel(
    const float* __restrict__ x, const float* __restrict__ xhat,
    float* __restrict__ sc)
{
  const size_t total4 = (size_t)N_ROWS * D_DIM / 4;
  const float4* x4  = (const float4*)x;
  const float4* xh4 = (const float4*)xhat;
  float recon = 0.f, uncap = 0.f;
  for (size_t i = (size_t)blockIdx.x * 256 + threadIdx.x; i < total4; i += (size_t)1024 * 256) {
    float4 a = x4[i], b = xh4[i];
    recon += b.x * b.x + b.y * b.y + b.z * b.z + b.w * b.w;
    float dx = a.x - b.x, dy = a.y - b.y, dz = a.z - b.z, dw = a.w - b.w;
    uncap += dx * dx + dy * dy + dz * dz + dw * dw;
  }
#pragma unroll
  for (int off = 32; off >= 1; off >>= 1) {
    recon += __shfl_down(recon, off);
    uncap += __shfl_down(uncap, off);
  }
  __shared__ float sR[4], sU[4];
  int wid = threadIdx.x >> 6, lane = threadIdx.x & 63;
  if (lane == 0) { sR[wid] = recon; sU[wid] = uncap; }
  __syncthreads();
  if (threadIdx.x == 0) {
    atomicAdd(&sc[1], sR[0] + sR[1] + sR[2] + sR[3]);
    atomicAdd(&sc[2], sU[0] + sU[1] + sU[2] + sU[3]);
  }
}

__global__ __launch_bounds__(128) void finalize_fb_kernel(
    const float* __restrict__ epart, const float* __restrict__ sc,
    float* __restrict__ out)
{
  const int t = threadIdx.x;
  __shared__ float sAvg[M_EXP];
  float s = 0.f;
  for (int c2 = 0; c2 < 64; ++c2) s += epart[c2 * M_EXP + t];
  sAvg[t] = s / (float)N_ROWS;
  __syncthreads();
  if (t == 0) {
    float denom = 0.f;
    for (int i = 0; i < M_EXP; ++i) denom += sAvg[i];
    if (denom < 1e-8f) denom = 1e-8f;
    float ent = 0.f;
    for (int i = 0; i < M_EXP; ++i) {
      float p = sAvg[i] / denom;
      if (p < 1e-8f) p = 1e-8f;
      ent += p * logf(p);
    }
    float bal   = -ent / logf(128.0f);
    float capt  = sc[0] / (float)N_ROWS;
    float recon = sc[1] / (float)N_ROWS;
    float uncap = sc[2] / (float)N_ROWS;
    out[SC_OFF + 0] = capt;
    out[SC_OFF + 1] = recon;
    out[SC_OFF + 2] = uncap;
    out[SC_OFF + 3] = bal;
    out[SC_OFF + 4] = uncap + 0.5f * (1.0f - bal);
  }
}

extern "C" void kernel_launch(void* const* d_in, const int* in_sizes, int n_in,
                              void* d_out, int out_size, void* d_ws, size_t ws_size,
                              hipStream_t stream) {
  const float* x = (const float*)d_in[0];
  const float* h = (const float*)d_in[1];
  const float* V = (const float*)d_in[2];
  float* out = (float*)d_out;
  char* ws = (char*)d_ws;

  if (ws_size >= F_NEED) {
    float* epart = (float*)(ws + F_EPART);
    int*   cnt   = (int*)(ws + F_CNT);
    int*   lists = (int*)(ws + F_LISTS);
    uint2* hsb   = (uint2*)(ws + F_HSB);
    uint4* Vb    = (uint4*)(ws + F_VB);
    uint4* y     = (uint4*)(ws + F_Y);
    float* capt_part  = (float*)(ws + F_CAPT);
    float* recon_part = (float*)(ws + F_RECON);
    float* uncap_part = (float*)(ws + F_UNCAP);

    zero_kernel<<<64, 256, 0, stream>>>((float*)ws);
    topk_kernel<<<12288, 256, 0, stream>>>(h, V, out, epart, cnt, lists, capt_part, hsb, Vb);
    b1_kernel<<<dim3(8, 128, 2), 256, 0, stream>>>(Vb, (const uint4*)hsb, cnt, lists, y);
    b2_kernel<<<4096, 256, 0, stream>>>(x, y, recon_part, uncap_part);
    finalize_kernel<<<1, 128, 0, stream>>>(epart, capt_part, recon_part, uncap_part, out);
  } else {
    float* xhat  = (float*)(ws + WS_XHAT);
    float* epart = (float*)(ws + WS_EPART);
    int*   cnt   = (int*)(ws + WS_CNT);
    float* sc    = (float*)(ws + WS_SC);
    int*   lists = (int*)(ws + WS_LISTS);

    hipMemsetAsync(d_ws, 0, WS_ZERO_BYTES, stream);
    topk_fb_kernel<<<N_ROWS, 128, 0, stream>>>(h, out, epart, cnt, lists, sc);
    xhat_kernel<<<dim3(8, 128, 16), 128, 0, stream>>>(V, out, cnt, lists, xhat);
    reduce_kernel<<<1024, 256, 0, stream>>>(x, xhat, sc);
    finalize_fb_kernel<<<1, 128, 0, stream>>>(epart, sc, out);
  }
}

// Round 15
// 176.353 us; speedup vs baseline: 1.0561x; 1.0561x over previous
//
#include <hip/hip_runtime.h>
#include <hip/hip_bf16.h>

#define N_ROWS 8192
#define D_DIM  1024
#define M_EXP  128
#define B_DIM  64
#define K_SEL  8

// ---- output layout (floats), in reference return order ----
#define HS_OFF  0                               // h_sparse: N*K*B
#define IDX_OFF (N_ROWS * K_SEL * B_DIM)        // topk_idxs as float: N*K
#define SC_OFF  (IDX_OFF + N_ROWS * K_SEL)      // 5 scalars

// ---- FAST-path workspace layout (bytes) ----
// epart: [t][s] 128x64 f32 (atomics spread); cnt: stride-64 ints
#define F_EPART   0                             // 32 KB
#define F_CNT     32768                         // 32 KB (spread x64)
#define F_ZERO    65536                         // bytes zeroed by zero_kernel
#define F_LISTS   65536                         // 128*8192 int (4 MB)
#define F_HSB     4259840                       // h_sparse bf16: 8 MB
#define F_VB      (F_HSB + 8388608)             // V bf16: 16 MB
#define F_Y       (F_VB + 16777216)             // 128 MB
#define F_CAPT    (F_Y + 134217728)             // 4096 f32 per-block capt partials
#define F_RECON   (F_CAPT + 16384)              // 4096 f32
#define F_UNCAP   (F_RECON + 16384)             // 4096 f32
#define F_NEED    (F_UNCAP + 16384)

// ---- FALLBACK workspace layout (bytes) ----
#define WS_XHAT   0
#define WS_EPART  33554432
#define WS_CNT    (33554432 + 32768)
#define WS_SC     (WS_CNT + 512)
#define WS_ZERO_BYTES (WS_SC + 16)
#define WS_LISTS  WS_ZERO_BYTES

typedef __attribute__((ext_vector_type(8))) short bhalf8;
typedef __attribute__((ext_vector_type(4))) float f32x4;

__device__ __forceinline__ unsigned bfbits(float f) {
  unsigned u = __float_as_uint(f);
  return (u + 0x7FFFu + ((u >> 16) & 1u)) >> 16;   // RNE f32->bf16 (finite inputs)
}

// ============================================================
// zero_kernel: zero epart+cnt (must precede topk's atomics)
// ============================================================
__global__ __launch_bounds__(256) void zero_kernel(float* __restrict__ ws) {
  int i = blockIdx.x * 256 + threadIdx.x;
  if (i < (F_ZERO / 4)) ws[i] = 0.f;
}

// ============================================================
// Kernel A (R11 2-row topk + EMBEDDED V convert as ILP):
// grid 4096 x 256. Each thread also owns 8 floats of V: loads
// issued at entry (in flight across all topk phases), bf16
// convert + store at exit. No separate convert blocks/tail.
// ============================================================
__global__ __launch_bounds__(256) void topk_kernel(
    const float* __restrict__ h, const float* __restrict__ V,
    float* __restrict__ out,
    float* __restrict__ epart, int* __restrict__ cnt,
    int* __restrict__ lists, float* __restrict__ capt_part,
    uint2* __restrict__ hsb, uint4* __restrict__ Vb)
{
#pragma clang fp contract(off)
  const int t  = threadIdx.x;
  const int n0 = blockIdx.x * 2;

  __shared__ float4 buf[2][2048];   // 64 KB
  __shared__ float  sE[2][M_EXP];
  __shared__ int    sIdx[2][K_SEL];
  __shared__ float  sCapt[2];

  // ---- issue V-convert loads early: in flight across all phases ----
  const int vk = blockIdx.x * 256 + t;             // 4096*256 threads x 8 floats = all of V
  const float4* vp = (const float4*)V + (size_t)vk * 2;
  float4 va = vp[0], vb = vp[1];

  const float4* hb = (const float4*)h;
  {
    float4 v[16];
#pragma unroll
    for (int r = 0; r < 2; ++r) {
      const float4* hrow = hb + (size_t)(n0 + r) * 2048;
#pragma unroll
      for (int f = 0; f < 8; ++f) v[r * 8 + f] = hrow[f * 256 + t];
    }
#pragma unroll
    for (int r = 0; r < 2; ++r)
#pragma unroll
      for (int f = 0; f < 8; ++f) {
        const int G = f * 256 + t;
        const int e = G >> 4, c = G & 15;
        buf[r][e * 16 + (c ^ (e & 7))] = v[r * 8 + f];
      }
  }
  __syncthreads();

  {
    const int r = t >> 7, e = t & 127;
    const float4* bp = buf[r];
    const int base = e * 16, sw = e & 7;
    float r0=0.f,r1=0.f,r2=0.f,r3=0.f,r4=0.f,r5=0.f,r6=0.f,r7=0.f;
#pragma unroll
    for (int c = 0; c < 16; c += 2) {
      float4 a = bp[base + (c ^ sw)];
      float4 b = bp[base + ((c + 1) ^ sw)];
      r0 += a.x * a.x;  r1 += a.y * a.y;  r2 += a.z * a.z;  r3 += a.w * a.w;
      r4 += b.x * b.x;  r5 += b.y * b.y;  r6 += b.z * b.z;  r7 += b.w * b.w;
    }
    sE[r][e] = ((r0 + r1) + (r2 + r3)) + ((r4 + r5) + (r6 + r7));
  }
  __syncthreads();

  // epart [t][s]: block's 128 atomics land on 128 distinct cache lines
  if (t < 128) atomicAdd(&epart[t * 64 + (blockIdx.x & 63)], sE[0][t] + sE[1][t]);

  if ((t & 64) == 0) {
    const int r = t >> 7, lane = t & 63;
    float ea = sE[r][lane];
    float eb = sE[r][lane + 64];
    float capt = 0.f;
#pragma unroll
    for (int j = 0; j < K_SEL; ++j) {
      float v; int idx;
      if (eb > ea) { v = eb; idx = lane + 64; } else { v = ea; idx = lane; }
#pragma unroll
      for (int off = 32; off >= 1; off >>= 1) {
        float ov = __shfl_xor(v, off);
        int   oi = __shfl_xor(idx, off);
        if (ov > v || (ov == v && oi < idx)) { v = ov; idx = oi; }
      }
      if (lane == 0) sIdx[r][j] = idx;
      if (idx == lane)      ea = -3.402823466e38f;
      if (idx == lane + 64) eb = -3.402823466e38f;
      capt += v;
    }
    if (lane == 0) sCapt[r] = capt;
  }
  __syncthreads();

  if (t == 0) capt_part[blockIdx.x] = sCapt[0] + sCapt[1];

  if (t < 16) {
    const int r = t >> 3, j = t & 7;
    const int n = n0 + r;
    const int ii = sIdx[r][j];
    out[IDX_OFF + n * K_SEL + j] = (float)ii;
    int pos = atomicAdd(&cnt[ii * 64], 1);    // stride-64: independent lines
    lists[ii * N_ROWS + pos] = (n << 3) | j;
  }

  // ---- gather h_sparse from LDS: f32 to out + bf16 to hsb ----
  {
    const int r = t >> 7, j = (t >> 4) & 7, c4 = t & 15;
    const int n = n0 + r;
    const int src = sIdx[r][j];
    float4 v = buf[r][src * 16 + (c4 ^ (src & 7))];
    ((float4*)out)[((size_t)n * K_SEL + j) * 16 + c4] = v;
    uint2 u;
    u.x = bfbits(v.x) | (bfbits(v.y) << 16);
    u.y = bfbits(v.z) | (bfbits(v.w) << 16);
    hsb[((size_t)n * K_SEL + j) * 16 + c4] = u;
  }

  // ---- V convert finish: loads long since landed; convert + store ----
  {
    uint4 u;
    u.x = bfbits(va.x) | (bfbits(va.y) << 16);
    u.y = bfbits(va.z) | (bfbits(va.w) << 16);
    u.z = bfbits(vb.x) | (bfbits(vb.y) << 16);
    u.w = bfbits(vb.z) | (bfbits(vb.w) << 16);
    Vb[vk] = u;
  }
}

// ============================================================
// FAST Kernel B1 (MFMA v3): swapped operands, z=2 chunks.
// grid (8 d-tiles, 128 experts, 2 chunks) x 256.
// ============================================================
__global__ __launch_bounds__(256, 2) void b1_kernel(
    const uint4* __restrict__ Vb, const uint4* __restrict__ hsb,
    const int* __restrict__ cnt, const int* __restrict__ lists,
    uint4* __restrict__ y)
{
  const int t  = threadIdx.x;
  const int d0 = blockIdx.x * 128;
  const int ex = blockIdx.y;
  const int c  = cnt[ex * 64];
  if ((int)(blockIdx.z * 128) >= c) return;

  __shared__ uint4 mem[2048];     // Vl (prologue) / Hl; Ol aliases all
  __shared__ int   qbuf[128];

  const int w = t >> 6, l = t & 63;
  const int l15 = l & 15, l4 = l >> 4;

  // ---- stage V tile once (bf16, swizzled): 2 threads / d-row ----
  {
    const int d = t >> 1, half = t & 1;
    const uint4* vp = Vb + (size_t)(d0 + d) * 1024 + ex * 8 + half * 4;
#pragma unroll
    for (int jj = 0; jj < 4; ++jj) {
      const int cI = half * 4 + jj;
      mem[d * 8 + (cI ^ (d & 7))] = vp[jj];
    }
  }
  __syncthreads();

  // ---- V fragments (A operand), reg-cached; Vl LDS dead afterwards ----
  bhalf8 vf[8][2];
#pragma unroll
  for (int dt = 0; dt < 8; ++dt)
#pragma unroll
    for (int kh = 0; kh < 2; ++kh) {
      const int d = dt * 16 + l15;
      const int kc = kh * 4 + l4;
      vf[dt][kh] = *(const bhalf8*)&mem[d * 8 + (kc ^ (d & 7))];
    }
  __syncthreads();

  for (int ybase = blockIdx.z * 128; ybase < c; ybase += 256) {
    const int rows = min(128, c - ybase);

    // ---- stage h rows (bf16, swizzled) into mem[1024..2047] ----
    {
      const int r = t >> 1, half = t & 1;
      if (r < rows) {
        const int q = lists[ex * N_ROWS + ybase + r];
        if (half == 0) qbuf[r] = q;
        const uint4* hp = hsb + (size_t)q * 8 + half * 4;
#pragma unroll
        for (int jj = 0; jj < 4; ++jj) {
          const int cI = half * 4 + jj;
          mem[1024 + r * 8 + (cI ^ (r & 7))] = hp[jj];
        }
      }
    }
    __syncthreads();

    // ---- h fragments (B operand) ----
    bhalf8 hf[2][2];
#pragma unroll
    for (int rt = 0; rt < 2; ++rt)
#pragma unroll
      for (int kh = 0; kh < 2; ++kh) {
        const int r = w * 32 + rt * 16 + l15;
        const int kc = kh * 4 + l4;
        hf[rt][kh] = *(const bhalf8*)&mem[1024 + r * 8 + (kc ^ (r & 7))];
      }

    f32x4 acc[2][8];
#pragma unroll
    for (int rt = 0; rt < 2; ++rt)
#pragma unroll
      for (int dt = 0; dt < 8; ++dt)
        acc[rt][dt] = (f32x4){0.f, 0.f, 0.f, 0.f};

#pragma unroll
    for (int kh = 0; kh < 2; ++kh)
#pragma unroll
      for (int rt = 0; rt < 2; ++rt)
#pragma unroll
        for (int dt = 0; dt < 8; ++dt)
          acc[rt][dt] = __builtin_amdgcn_mfma_f32_16x16x32_bf16(
              vf[dt][kh], hf[rt][kh], acc[rt][dt], 0, 0, 0);

    __syncthreads();   // all Hl reads done; Ol may overwrite mem

    // ---- D -> Ol: lane holds 4 consecutive d-cols of one local row ----
    {
      uint2* Ol2 = (uint2*)mem;
#pragma unroll
      for (int rt = 0; rt < 2; ++rt) {
        const int j2 = w * 32 + rt * 16 + l15;
#pragma unroll
        for (int dt = 0; dt < 8; ++dt) {
          const f32x4 a = acc[rt][dt];
          uint2 u;
          u.x = bfbits(a[0]) | (bfbits(a[1]) << 16);
          u.y = bfbits(a[2]) | (bfbits(a[3]) << 16);
          const int ch = dt * 2 + (l4 >> 1);          // 16B chunk = col/8
          Ol2[j2 * 32 + ((ch ^ (j2 & 7)) << 1) + (l4 & 1)] = u;
        }
      }
    }
    __syncthreads();

    // ---- coalesced y stores: 16 threads/row ----
    {
      const int rloc = t >> 4, cI = t & 15;
#pragma unroll
      for (int p = 0; p < 8; ++p) {
        const int row = p * 16 + rloc;
        if (row < rows)
          y[(size_t)qbuf[row] * 128 + blockIdx.x * 16 + cI] =
              mem[row * 16 + (cI ^ (row & 7))];
      }
    }
    __syncthreads();   // before next iteration restages Hl over Ol
  }
}

// ============================================================
// FAST Kernel B2: fold y over j -> x_hat in regs -> recon/uncap.
// ============================================================
__global__ __launch_bounds__(256) void b2_kernel(
    const float* __restrict__ x, const uint4* __restrict__ y,
    float* __restrict__ recon_part, float* __restrict__ uncap_part)
{
  const int tid = blockIdx.x * 256 + threadIdx.x;
  const int n = tid >> 7, dc = tid & 127;

  float xh[8] = {0.f,0.f,0.f,0.f,0.f,0.f,0.f,0.f};
  const uint4* yp = y + (size_t)n * (8 * 128) + dc;
#pragma unroll
  for (int j = 0; j < 8; ++j) {
    uint4 u = yp[(size_t)j * 128];
    xh[0] += __uint_as_float(u.x << 16);
    xh[1] += __uint_as_float(u.x & 0xFFFF0000u);
    xh[2] += __uint_as_float(u.y << 16);
    xh[3] += __uint_as_float(u.y & 0xFFFF0000u);
    xh[4] += __uint_as_float(u.z << 16);
    xh[5] += __uint_as_float(u.z & 0xFFFF0000u);
    xh[6] += __uint_as_float(u.w << 16);
    xh[7] += __uint_as_float(u.w & 0xFFFF0000u);
  }
  const float4* xp = (const float4*)(x + (size_t)n * D_DIM + dc * 8);
  float4 a0 = xp[0], a1 = xp[1];
  float xv[8] = {a0.x, a0.y, a0.z, a0.w, a1.x, a1.y, a1.z, a1.w};

  float recon = 0.f, uncap = 0.f;
#pragma unroll
  for (int i = 0; i < 8; ++i) {
    recon += xh[i] * xh[i];
    float dd = xv[i] - xh[i];
    uncap += dd * dd;
  }

#pragma unroll
  for (int off = 32; off >= 1; off >>= 1) {
    recon += __shfl_down(recon, off);
    uncap += __shfl_down(uncap, off);
  }
  __shared__ float sR[4], sU[4];
  int wid = threadIdx.x >> 6, lane = threadIdx.x & 63;
  if (lane == 0) { sR[wid] = recon; sU[wid] = uncap; }
  __syncthreads();
  if (threadIdx.x == 0) {
    recon_part[blockIdx.x] = sR[0] + sR[1] + sR[2] + sR[3];
    uncap_part[blockIdx.x] = sU[0] + sU[1] + sU[2] + sU[3];
  }
}

// ============================================================
// FAST finalize: sum partials + entropy + scalars (epart [t][s])
// ============================================================
__global__ __launch_bounds__(128) void finalize_kernel(
    const float* __restrict__ epart, const float* __restrict__ capt_part,
    const float* __restrict__ recon_part, const float* __restrict__ uncap_part,
    float* __restrict__ out)
{
  const int t = threadIdx.x;
  __shared__ float sAvg[M_EXP];
  __shared__ float red[3][2];

  float s = 0.f;
  for (int c2 = 0; c2 < 64; ++c2) s += epart[t * 64 + c2];
  sAvg[t] = s / (float)N_ROWS;

  float pc = 0.f, pr = 0.f, pu = 0.f;
  for (int i = t; i < 4096; i += 128) {
    pc += capt_part[i];
    pr += recon_part[i];
    pu += uncap_part[i];
  }
#pragma unroll
  for (int off = 32; off >= 1; off >>= 1) {
    pc += __shfl_down(pc, off);
    pr += __shfl_down(pr, off);
    pu += __shfl_down(pu, off);
  }
  const int wid = t >> 6, lane = t & 63;
  if (lane == 0) { red[0][wid] = pc; red[1][wid] = pr; red[2][wid] = pu; }
  __syncthreads();

  if (t == 0) {
    float denom = 0.f;
    for (int i = 0; i < M_EXP; ++i) denom += sAvg[i];
    if (denom < 1e-8f) denom = 1e-8f;
    float ent = 0.f;
    for (int i = 0; i < M_EXP; ++i) {
      float p = sAvg[i] / denom;
      if (p < 1e-8f) p = 1e-8f;
      ent += p * logf(p);
    }
    float bal   = -ent / logf(128.0f);
    float capt  = (red[0][0] + red[0][1]) / (float)N_ROWS;
    float recon = (red[1][0] + red[1][1]) / (float)N_ROWS;
    float uncap = (red[2][0] + red[2][1]) / (float)N_ROWS;
    out[SC_OFF + 0] = capt;
    out[SC_OFF + 1] = recon;
    out[SC_OFF + 2] = uncap;
    out[SC_OFF + 3] = bal;
    out[SC_OFF + 4] = uncap + 0.5f * (1.0f - bal);
  }
}

// ============================================================
// FALLBACK kernels (only used if ws too small)
// ============================================================
__global__ __launch_bounds__(128) void topk_fb_kernel(
    const float* __restrict__ h, float* __restrict__ out,
    float* __restrict__ epart, int* __restrict__ cnt,
    int* __restrict__ lists, float* __restrict__ sc)
{
#pragma clang fp contract(off)
  const int n = blockIdx.x;
  const int t = threadIdx.x;
  __shared__ float sE[M_EXP];
  __shared__ int   sIdx[K_SEL];
  const float4* hp = (const float4*)(h + (size_t)n * (M_EXP * B_DIM) + t * B_DIM);
  float r0=0.f,r1=0.f,r2=0.f,r3=0.f,r4=0.f,r5=0.f,r6=0.f,r7=0.f;
#pragma unroll
  for (int f = 0; f < 16; f += 2) {
    float4 a = hp[f];
    float4 b = hp[f + 1];
    r0 += a.x * a.x;  r1 += a.y * a.y;  r2 += a.z * a.z;  r3 += a.w * a.w;
    r4 += b.x * b.x;  r5 += b.y * b.y;  r6 += b.z * b.z;  r7 += b.w * b.w;
  }
  const float e = ((r0 + r1) + (r2 + r3)) + ((r4 + r5) + (r6 + r7));
  sE[t] = e;
  atomicAdd(&epart[(n & 63) * M_EXP + t], e);
  __syncthreads();
  if (t < 64) {
    float ea = sE[t], eb = sE[t + 64], capt = 0.f;
#pragma unroll
    for (int j = 0; j < K_SEL; ++j) {
      float v; int idx;
      if (eb > ea) { v = eb; idx = t + 64; } else { v = ea; idx = t; }
#pragma unroll
      for (int off = 32; off >= 1; off >>= 1) {
        float ov = __shfl_xor(v, off);
        int   oi = __shfl_xor(idx, off);
        if (ov > v || (ov == v && oi < idx)) { v = ov; idx = oi; }
      }
      if (t == 0) sIdx[j] = idx;
      if (idx == t)      ea = -3.402823466e38f;
      if (idx == t + 64) eb = -3.402823466e38f;
      capt += v;
    }
    if (t == 0) atomicAdd(&sc[0], capt);
  }
  __syncthreads();
  if (t < K_SEL) {
    int ii = sIdx[t];
    out[IDX_OFF + n * K_SEL + t] = (float)ii;
    int pos = atomicAdd(&cnt[ii], 1);
    lists[ii * N_ROWS + pos] = (n << 3) | t;
  }
  {
    int j = t >> 4, c4 = t & 15;
    int src = sIdx[j];
    const float4* gp = (const float4*)(h + (size_t)n * (M_EXP * B_DIM) + src * B_DIM);
    float4 v = gp[c4];
    ((float4*)(out + (size_t)n * (K_SEL * B_DIM) + j * B_DIM))[c4] = v;
  }
}

__global__ __launch_bounds__(128) void xhat_kernel(
    const float* __restrict__ V, const float* __restrict__ out,
    const int* __restrict__ cnt, const int* __restrict__ lists,
    float* __restrict__ xhat)
{
  const int t  = threadIdx.x;
  const int d0 = blockIdx.x * 128;
  const int ex = blockIdx.y;
  const int ybase = blockIdx.z * 512;
  const int c = cnt[ex];
  if (ybase >= c) return;
  const int rowsChunk = min(512, c - ybase);
  __shared__ float Vt[64 * 132];
  __shared__ float hvT[64 * 68];
  __shared__ int   nbuf[64];
  {
    const float4* vp = (const float4*)(V + (size_t)(d0 + t) * (M_EXP * B_DIM) + ex * B_DIM);
    const int colt = t + ((t >> 6) << 2);
#pragma unroll
    for (int f = 0; f < 16; ++f) {
      float4 vv = vp[f];
      int b = f * 4;
      Vt[(b + 0) * 132 + colt] = vv.x;
      Vt[(b + 1) * 132 + colt] = vv.y;
      Vt[(b + 2) * 132 + colt] = vv.z;
      Vt[(b + 3) * 132 + colt] = vv.w;
    }
  }
  const int rg = t >> 4, dg = t & 15;
  const int hvBase = rg * 8;
  const int vBase  = dg * 8 + ((dg >> 3) << 2);
  for (int it = 0; it * 64 < rowsChunk; ++it) {
    const int rows = min(64, rowsChunk - it * 64);
    {
      const int r = t >> 1, half = t & 1;
      if (r < rows) {
        int q = lists[ex * N_ROWS + ybase + it * 64 + r];
        int nn = q >> 3, jj = q & 7;
        if (half == 0) nbuf[r] = nn;
        const float4* hp = (const float4*)(out + ((size_t)nn * K_SEL + jj) * B_DIM + half * 32);
#pragma unroll
        for (int f = 0; f < 8; ++f) {
          float4 hv = hp[f];
          int b = half * 32 + f * 4;
          hvT[(b + 0) * 68 + r] = hv.x;
          hvT[(b + 1) * 68 + r] = hv.y;
          hvT[(b + 2) * 68 + r] = hv.z;
          hvT[(b + 3) * 68 + r] = hv.w;
        }
      } else {
        if (half == 0) nbuf[r] = 0;
#pragma unroll
        for (int f = 0; f < 8; ++f) {
          int b = half * 32 + f * 4;
          hvT[(b + 0) * 68 + r] = 0.f;
          hvT[(b + 1) * 68 + r] = 0.f;
          hvT[(b + 2) * 68 + r] = 0.f;
          hvT[(b + 3) * 68 + r] = 0.f;
        }
      }
    }
    __syncthreads();
    float acc[8][8];
#pragma unroll
    for (int a = 0; a < 8; ++a)
#pragma unroll
      for (int d = 0; d < 8; ++d) acc[a][d] = 0.f;
#pragma unroll 4
    for (int b = 0; b < 64; ++b) {
      float4 h0 = *(const float4*)&hvT[b * 68 + hvBase];
      float4 h1 = *(const float4*)&hvT[b * 68 + hvBase + 4];
      float4 v0 = *(const float4*)&Vt[b * 132 + vBase];
      float4 v1 = *(const float4*)&Vt[b * 132 + vBase + 4];
      float hv[8] = {h0.x, h0.y, h0.z, h0.w, h1.x, h1.y, h1.z, h1.w};
      float vv[8] = {v0.x, v0.y, v0.z, v0.w, v1.x, v1.y, v1.z, v1.w};
#pragma unroll
      for (int a = 0; a < 8; ++a)
#pragma unroll
        for (int d = 0; d < 8; ++d)
          acc[a][d] = fmaf(hv[a], vv[d], acc[a][d]);
    }
#pragma unroll
    for (int a = 0; a < 8; ++a) {
      int r2 = rg * 8 + a;
      if (r2 < rows) {
        float* xp = xhat + (size_t)nbuf[r2] * D_DIM + d0 + dg * 8;
#pragma unroll
        for (int d = 0; d < 8; ++d) atomicAdd(xp + d, acc[a][d]);
      }
    }
    __syncthreads();
  }
}

__global__ __launch_bounds__(256) void reduce_kernel(
    const float* __restrict__ x, const float* __restrict__ xhat,
    float* __restrict__ sc)
{
  const size_t total4 = (size_t)N_ROWS * D_DIM / 4;
  const float4* x4  = (const float4*)x;
  const float4* xh4 = (const float4*)xhat;
  float recon = 0.f, uncap = 0.f;
  for (size_t i = (size_t)blockIdx.x * 256 + threadIdx.x; i < total4; i += (size_t)1024 * 256) {
    float4 a = x4[i], b = xh4[i];
    recon += b.x * b.x + b.y * b.y + b.z * b.z + b.w * b.w;
    float dx = a.x - b.x, dy = a.y - b.y, dz = a.z - b.z, dw = a.w - b.w;
    uncap += dx * dx + dy * dy + dz * dz + dw * dw;
  }
#pragma unroll
  for (int off = 32; off >= 1; off >>= 1) {
    recon += __shfl_down(recon, off);
    uncap += __shfl_down(uncap, off);
  }
  __shared__ float sR[4], sU[4];
  int wid = threadIdx.x >> 6, lane = threadIdx.x & 63;
  if (lane == 0) { sR[wid] = recon; sU[wid] = uncap; }
  __syncthreads();
  if (threadIdx.x == 0) {
    atomicAdd(&sc[1], sR[0] + sR[1] + sR[2] + sR[3]);
    atomicAdd(&sc[2], sU[0] + sU[1] + sU[2] + sU[3]);
  }
}

__global__ __launch_bounds__(128) void finalize_fb_kernel(
    const float* __restrict__ epart, const float* __restrict__ sc,
    float* __restrict__ out)
{
  const int t = threadIdx.x;
  __shared__ float sAvg[M_EXP];
  float s = 0.f;
  for (int c2 = 0; c2 < 64; ++c2) s += epart[c2 * M_EXP + t];
  sAvg[t] = s / (float)N_ROWS;
  __syncthreads();
  if (t == 0) {
    float denom = 0.f;
    for (int i = 0; i < M_EXP; ++i) denom += sAvg[i];
    if (denom < 1e-8f) denom = 1e-8f;
    float ent = 0.f;
    for (int i = 0; i < M_EXP; ++i) {
      float p = sAvg[i] / denom;
      if (p < 1e-8f) p = 1e-8f;
      ent += p * logf(p);
    }
    float bal   = -ent / logf(128.0f);
    float capt  = sc[0] / (float)N_ROWS;
    float recon = sc[1] / (float)N_ROWS;
    float uncap = sc[2] / (float)N_ROWS;
    out[SC_OFF + 0] = capt;
    out[SC_OFF + 1] = recon;
    out[SC_OFF + 2] = uncap;
    out[SC_OFF + 3] = bal;
    out[SC_OFF + 4] = uncap + 0.5f * (1.0f - bal);
  }
}

extern "C" void kernel_launch(void* const* d_in, const int* in_sizes, int n_in,
                              void* d_out, int out_size, void* d_ws, size_t ws_size,
                              hipStream_t stream) {
  const float* x = (const float*)d_in[0];
  const float* h = (const float*)d_in[1];
  const float* V = (const float*)d_in[2];
  float* out = (float*)d_out;
  char* ws = (char*)d_ws;

  if (ws_size >= F_NEED) {
    float* epart = (float*)(ws + F_EPART);
    int*   cnt   = (int*)(ws + F_CNT);
    int*   lists = (int*)(ws + F_LISTS);
    uint2* hsb   = (uint2*)(ws + F_HSB);
    uint4* Vb    = (uint4*)(ws + F_VB);
    uint4* y     = (uint4*)(ws + F_Y);
    float* capt_part  = (float*)(ws + F_CAPT);
    float* recon_part = (float*)(ws + F_RECON);
    float* uncap_part = (float*)(ws + F_UNCAP);

    zero_kernel<<<64, 256, 0, stream>>>((float*)ws);
    topk_kernel<<<4096, 256, 0, stream>>>(h, V, out, epart, cnt, lists, capt_part, hsb, Vb);
    b1_kernel<<<dim3(8, 128, 2), 256, 0, stream>>>(Vb, (const uint4*)hsb, cnt, lists, y);
    b2_kernel<<<4096, 256, 0, stream>>>(x, y, recon_part, uncap_part);
    finalize_kernel<<<1, 128, 0, stream>>>(epart, capt_part, recon_part, uncap_part, out);
  } else {
    float* xhat  = (float*)(ws + WS_XHAT);
    float* epart = (float*)(ws + WS_EPART);
    int*   cnt   = (int*)(ws + WS_CNT);
    float* sc    = (float*)(ws + WS_SC);
    int*   lists = (int*)(ws + WS_LISTS);

    hipMemsetAsync(d_ws, 0, WS_ZERO_BYTES, stream);
    topk_fb_kernel<<<N_ROWS, 128, 0, stream>>>(h, out, epart, cnt, lists, sc);
    xhat_kernel<<<dim3(8, 128, 16), 128, 0, stream>>>(V, out, cnt, lists, xhat);
    reduce_kernel<<<1024, 256, 0, stream>>>(x, xhat, sc);
    finalize_fb_kernel<<<1, 128, 0, stream>>>(epart, sc, out);
  }
}

// Round 16
// 175.858 us; speedup vs baseline: 1.0591x; 1.0028x over previous
//
#include <hip/hip_runtime.h>
#include <hip/hip_bf16.h>

#define N_ROWS 8192
#define D_DIM  1024
#define M_EXP  128
#define B_DIM  64
#define K_SEL  8

// ---- output layout (floats), in reference return order ----
#define HS_OFF  0                               // h_sparse: N*K*B
#define IDX_OFF (N_ROWS * K_SEL * B_DIM)        // topk_idxs as float: N*K
#define SC_OFF  (IDX_OFF + N_ROWS * K_SEL)      // 5 scalars

// ---- FAST-path workspace layout (bytes) ----
// epart: [t][s] 128x64 f32 (atomics spread); cnt: stride-64 ints
#define F_EPART   0                             // 32 KB
#define F_CNT     32768                         // 32 KB (spread x64)
#define F_ZERO    65536                         // bytes zeroed by zero_kernel
#define F_LISTS   65536                         // 128*8192 int (4 MB)
#define F_HSB     4259840                       // h_sparse bf16: 8 MB
#define F_VB      (F_HSB + 8388608)             // V bf16: 16 MB
#define F_Y       (F_VB + 16777216)             // 128 MB
#define F_CAPT    (F_Y + 134217728)             // 4096 f32 per-block capt partials
#define F_RECON   (F_CAPT + 16384)              // 4096 f32
#define F_UNCAP   (F_RECON + 16384)             // 4096 f32
#define F_NEED    (F_UNCAP + 16384)

// ---- FALLBACK workspace layout (bytes) ----
#define WS_XHAT   0
#define WS_EPART  33554432
#define WS_CNT    (33554432 + 32768)
#define WS_SC     (WS_CNT + 512)
#define WS_ZERO_BYTES (WS_SC + 16)
#define WS_LISTS  WS_ZERO_BYTES

typedef __attribute__((ext_vector_type(8))) short bhalf8;
typedef __attribute__((ext_vector_type(4))) float f32x4;

__device__ __forceinline__ unsigned bfbits(float f) {
  unsigned u = __float_as_uint(f);
  return (u + 0x7FFFu + ((u >> 16) & 1u)) >> 16;   // RNE f32->bf16 (finite inputs)
}

// ============================================================
// zero_kernel: zero epart+cnt (must precede topk's atomics)
// ============================================================
__global__ __launch_bounds__(256) void zero_kernel(float* __restrict__ ws) {
  int i = blockIdx.x * 256 + threadIdx.x;
  if (i < (F_ZERO / 4)) ws[i] = 0.f;
}

// ============================================================
// Kernel A (2-row topk + embedded V convert as ILP): grid 4096 x 256.
// ============================================================
__global__ __launch_bounds__(256) void topk_kernel(
    const float* __restrict__ h, const float* __restrict__ V,
    float* __restrict__ out,
    float* __restrict__ epart, int* __restrict__ cnt,
    int* __restrict__ lists, float* __restrict__ capt_part,
    uint2* __restrict__ hsb, uint4* __restrict__ Vb)
{
#pragma clang fp contract(off)
  const int t  = threadIdx.x;
  const int n0 = blockIdx.x * 2;

  __shared__ float4 buf[2][2048];   // 64 KB
  __shared__ float  sE[2][M_EXP];
  __shared__ int    sIdx[2][K_SEL];
  __shared__ float  sCapt[2];

  // ---- issue V-convert loads early: in flight across all phases ----
  const int vk = blockIdx.x * 256 + t;             // 4096*256 threads x 8 floats = all of V
  const float4* vp = (const float4*)V + (size_t)vk * 2;
  float4 va = vp[0], vb = vp[1];

  const float4* hb = (const float4*)h;
  {
    float4 v[16];
#pragma unroll
    for (int r = 0; r < 2; ++r) {
      const float4* hrow = hb + (size_t)(n0 + r) * 2048;
#pragma unroll
      for (int f = 0; f < 8; ++f) v[r * 8 + f] = hrow[f * 256 + t];
    }
#pragma unroll
    for (int r = 0; r < 2; ++r)
#pragma unroll
      for (int f = 0; f < 8; ++f) {
        const int G = f * 256 + t;
        const int e = G >> 4, c = G & 15;
        buf[r][e * 16 + (c ^ (e & 7))] = v[r * 8 + f];
      }
  }
  __syncthreads();

  {
    const int r = t >> 7, e = t & 127;
    const float4* bp = buf[r];
    const int base = e * 16, sw = e & 7;
    float r0=0.f,r1=0.f,r2=0.f,r3=0.f,r4=0.f,r5=0.f,r6=0.f,r7=0.f;
#pragma unroll
    for (int c = 0; c < 16; c += 2) {
      float4 a = bp[base + (c ^ sw)];
      float4 b = bp[base + ((c + 1) ^ sw)];
      r0 += a.x * a.x;  r1 += a.y * a.y;  r2 += a.z * a.z;  r3 += a.w * a.w;
      r4 += b.x * b.x;  r5 += b.y * b.y;  r6 += b.z * b.z;  r7 += b.w * b.w;
    }
    sE[r][e] = ((r0 + r1) + (r2 + r3)) + ((r4 + r5) + (r6 + r7));
  }
  __syncthreads();

  // epart [t][s]: block's 128 atomics land on 128 distinct cache lines
  if (t < 128) atomicAdd(&epart[t * 64 + (blockIdx.x & 63)], sE[0][t] + sE[1][t]);

  if ((t & 64) == 0) {
    const int r = t >> 7, lane = t & 63;
    float ea = sE[r][lane];
    float eb = sE[r][lane + 64];
    float capt = 0.f;
#pragma unroll
    for (int j = 0; j < K_SEL; ++j) {
      float v; int idx;
      if (eb > ea) { v = eb; idx = lane + 64; } else { v = ea; idx = lane; }
#pragma unroll
      for (int off = 32; off >= 1; off >>= 1) {
        float ov = __shfl_xor(v, off);
        int   oi = __shfl_xor(idx, off);
        if (ov > v || (ov == v && oi < idx)) { v = ov; idx = oi; }
      }
      if (lane == 0) sIdx[r][j] = idx;
      if (idx == lane)      ea = -3.402823466e38f;
      if (idx == lane + 64) eb = -3.402823466e38f;
      capt += v;
    }
    if (lane == 0) sCapt[r] = capt;
  }
  __syncthreads();

  if (t == 0) capt_part[blockIdx.x] = sCapt[0] + sCapt[1];

  if (t < 16) {
    const int r = t >> 3, j = t & 7;
    const int n = n0 + r;
    const int ii = sIdx[r][j];
    out[IDX_OFF + n * K_SEL + j] = (float)ii;
    int pos = atomicAdd(&cnt[ii * 64], 1);    // stride-64: independent lines
    lists[ii * N_ROWS + pos] = (n << 3) | j;
  }

  // ---- gather h_sparse from LDS: f32 to out + bf16 to hsb ----
  {
    const int r = t >> 7, j = (t >> 4) & 7, c4 = t & 15;
    const int n = n0 + r;
    const int src = sIdx[r][j];
    float4 v = buf[r][src * 16 + (c4 ^ (src & 7))];
    ((float4*)out)[((size_t)n * K_SEL + j) * 16 + c4] = v;
    uint2 u;
    u.x = bfbits(v.x) | (bfbits(v.y) << 16);
    u.y = bfbits(v.z) | (bfbits(v.w) << 16);
    hsb[((size_t)n * K_SEL + j) * 16 + c4] = u;
  }

  // ---- V convert finish: loads long since landed; convert + store ----
  {
    uint4 u;
    u.x = bfbits(va.x) | (bfbits(va.y) << 16);
    u.y = bfbits(va.z) | (bfbits(va.w) << 16);
    u.z = bfbits(vb.x) | (bfbits(vb.y) << 16);
    u.w = bfbits(vb.z) | (bfbits(vb.w) << 16);
    Vb[vk] = u;
  }
}

// ============================================================
// FAST Kernel B1 (MFMA v3): swapped operands, z=1 (V staged ONCE
// per (d-tile, expert); halves Vb re-reads vs z=2).
// grid (8 d-tiles, 128 experts) x 256.
// ============================================================
__global__ __launch_bounds__(256, 2) void b1_kernel(
    const uint4* __restrict__ Vb, const uint4* __restrict__ hsb,
    const int* __restrict__ cnt, const int* __restrict__ lists,
    uint4* __restrict__ y)
{
  const int t  = threadIdx.x;
  const int d0 = blockIdx.x * 128;
  const int ex = blockIdx.y;
  const int c  = cnt[ex * 64];
  if (c == 0) return;

  __shared__ uint4 mem[2048];     // Vl (prologue) / Hl; Ol aliases all
  __shared__ int   qbuf[128];

  const int w = t >> 6, l = t & 63;
  const int l15 = l & 15, l4 = l >> 4;

  // ---- stage V tile once (bf16, swizzled): 2 threads / d-row ----
  {
    const int d = t >> 1, half = t & 1;
    const uint4* vp = Vb + (size_t)(d0 + d) * 1024 + ex * 8 + half * 4;
#pragma unroll
    for (int jj = 0; jj < 4; ++jj) {
      const int cI = half * 4 + jj;
      mem[d * 8 + (cI ^ (d & 7))] = vp[jj];
    }
  }
  __syncthreads();

  // ---- V fragments (A operand), reg-cached; Vl LDS dead afterwards ----
  bhalf8 vf[8][2];
#pragma unroll
  for (int dt = 0; dt < 8; ++dt)
#pragma unroll
    for (int kh = 0; kh < 2; ++kh) {
      const int d = dt * 16 + l15;
      const int kc = kh * 4 + l4;
      vf[dt][kh] = *(const bhalf8*)&mem[d * 8 + (kc ^ (d & 7))];
    }
  __syncthreads();

  for (int ybase = 0; ybase < c; ybase += 128) {
    const int rows = min(128, c - ybase);

    // ---- stage h rows (bf16, swizzled) into mem[1024..2047] ----
    {
      const int r = t >> 1, half = t & 1;
      if (r < rows) {
        const int q = lists[ex * N_ROWS + ybase + r];
        if (half == 0) qbuf[r] = q;
        const uint4* hp = hsb + (size_t)q * 8 + half * 4;
#pragma unroll
        for (int jj = 0; jj < 4; ++jj) {
          const int cI = half * 4 + jj;
          mem[1024 + r * 8 + (cI ^ (r & 7))] = hp[jj];
        }
      }
    }
    __syncthreads();

    // ---- h fragments (B operand) ----
    bhalf8 hf[2][2];
#pragma unroll
    for (int rt = 0; rt < 2; ++rt)
#pragma unroll
      for (int kh = 0; kh < 2; ++kh) {
        const int r = w * 32 + rt * 16 + l15;
        const int kc = kh * 4 + l4;
        hf[rt][kh] = *(const bhalf8*)&mem[1024 + r * 8 + (kc ^ (r & 7))];
      }

    f32x4 acc[2][8];
#pragma unroll
    for (int rt = 0; rt < 2; ++rt)
#pragma unroll
      for (int dt = 0; dt < 8; ++dt)
        acc[rt][dt] = (f32x4){0.f, 0.f, 0.f, 0.f};

#pragma unroll
    for (int kh = 0; kh < 2; ++kh)
#pragma unroll
      for (int rt = 0; rt < 2; ++rt)
#pragma unroll
        for (int dt = 0; dt < 8; ++dt)
          acc[rt][dt] = __builtin_amdgcn_mfma_f32_16x16x32_bf16(
              vf[dt][kh], hf[rt][kh], acc[rt][dt], 0, 0, 0);

    __syncthreads();   // all Hl reads done; Ol may overwrite mem

    // ---- D -> Ol: lane holds 4 consecutive d-cols of one local row ----
    {
      uint2* Ol2 = (uint2*)mem;
#pragma unroll
      for (int rt = 0; rt < 2; ++rt) {
        const int j2 = w * 32 + rt * 16 + l15;
#pragma unroll
        for (int dt = 0; dt < 8; ++dt) {
          const f32x4 a = acc[rt][dt];
          uint2 u;
          u.x = bfbits(a[0]) | (bfbits(a[1]) << 16);
          u.y = bfbits(a[2]) | (bfbits(a[3]) << 16);
          const int ch = dt * 2 + (l4 >> 1);          // 16B chunk = col/8
          Ol2[j2 * 32 + ((ch ^ (j2 & 7)) << 1) + (l4 & 1)] = u;
        }
      }
    }
    __syncthreads();

    // ---- coalesced y stores: 16 threads/row ----
    {
      const int rloc = t >> 4, cI = t & 15;
#pragma unroll
      for (int p = 0; p < 8; ++p) {
        const int row = p * 16 + rloc;
        if (row < rows)
          y[(size_t)qbuf[row] * 128 + blockIdx.x * 16 + cI] =
              mem[row * 16 + (cI ^ (row & 7))];
      }
    }
    __syncthreads();   // before next iteration restages Hl over Ol
  }
}

// ============================================================
// FAST Kernel B2: fold y over j -> x_hat in regs -> recon/uncap.
// ============================================================
__global__ __launch_bounds__(256) void b2_kernel(
    const float* __restrict__ x, const uint4* __restrict__ y,
    float* __restrict__ recon_part, float* __restrict__ uncap_part)
{
  const int tid = blockIdx.x * 256 + threadIdx.x;
  const int n = tid >> 7, dc = tid & 127;

  float xh[8] = {0.f,0.f,0.f,0.f,0.f,0.f,0.f,0.f};
  const uint4* yp = y + (size_t)n * (8 * 128) + dc;
#pragma unroll
  for (int j = 0; j < 8; ++j) {
    uint4 u = yp[(size_t)j * 128];
    xh[0] += __uint_as_float(u.x << 16);
    xh[1] += __uint_as_float(u.x & 0xFFFF0000u);
    xh[2] += __uint_as_float(u.y << 16);
    xh[3] += __uint_as_float(u.y & 0xFFFF0000u);
    xh[4] += __uint_as_float(u.z << 16);
    xh[5] += __uint_as_float(u.z & 0xFFFF0000u);
    xh[6] += __uint_as_float(u.w << 16);
    xh[7] += __uint_as_float(u.w & 0xFFFF0000u);
  }
  const float4* xp = (const float4*)(x + (size_t)n * D_DIM + dc * 8);
  float4 a0 = xp[0], a1 = xp[1];
  float xv[8] = {a0.x, a0.y, a0.z, a0.w, a1.x, a1.y, a1.z, a1.w};

  float recon = 0.f, uncap = 0.f;
#pragma unroll
  for (int i = 0; i < 8; ++i) {
    recon += xh[i] * xh[i];
    float dd = xv[i] - xh[i];
    uncap += dd * dd;
  }

#pragma unroll
  for (int off = 32; off >= 1; off >>= 1) {
    recon += __shfl_down(recon, off);
    uncap += __shfl_down(uncap, off);
  }
  __shared__ float sR[4], sU[4];
  int wid = threadIdx.x >> 6, lane = threadIdx.x & 63;
  if (lane == 0) { sR[wid] = recon; sU[wid] = uncap; }
  __syncthreads();
  if (threadIdx.x == 0) {
    recon_part[blockIdx.x] = sR[0] + sR[1] + sR[2] + sR[3];
    uncap_part[blockIdx.x] = sU[0] + sU[1] + sU[2] + sU[3];
  }
}

// ============================================================
// FAST finalize: sum partials + entropy + scalars (epart [t][s])
// ============================================================
__global__ __launch_bounds__(128) void finalize_kernel(
    const float* __restrict__ epart, const float* __restrict__ capt_part,
    const float* __restrict__ recon_part, const float* __restrict__ uncap_part,
    float* __restrict__ out)
{
  const int t = threadIdx.x;
  __shared__ float sAvg[M_EXP];
  __shared__ float red[3][2];

  float s = 0.f;
  for (int c2 = 0; c2 < 64; ++c2) s += epart[t * 64 + c2];
  sAvg[t] = s / (float)N_ROWS;

  float pc = 0.f, pr = 0.f, pu = 0.f;
  for (int i = t; i < 4096; i += 128) {
    pc += capt_part[i];
    pr += recon_part[i];
    pu += uncap_part[i];
  }
#pragma unroll
  for (int off = 32; off >= 1; off >>= 1) {
    pc += __shfl_down(pc, off);
    pr += __shfl_down(pr, off);
    pu += __shfl_down(pu, off);
  }
  const int wid = t >> 6, lane = t & 63;
  if (lane == 0) { red[0][wid] = pc; red[1][wid] = pr; red[2][wid] = pu; }
  __syncthreads();

  if (t == 0) {
    float denom = 0.f;
    for (int i = 0; i < M_EXP; ++i) denom += sAvg[i];
    if (denom < 1e-8f) denom = 1e-8f;
    float ent = 0.f;
    for (int i = 0; i < M_EXP; ++i) {
      float p = sAvg[i] / denom;
      if (p < 1e-8f) p = 1e-8f;
      ent += p * logf(p);
    }
    float bal   = -ent / logf(128.0f);
    float capt  = (red[0][0] + red[0][1]) / (float)N_ROWS;
    float recon = (red[1][0] + red[1][1]) / (float)N_ROWS;
    float uncap = (red[2][0] + red[2][1]) / (float)N_ROWS;
    out[SC_OFF + 0] = capt;
    out[SC_OFF + 1] = recon;
    out[SC_OFF + 2] = uncap;
    out[SC_OFF + 3] = bal;
    out[SC_OFF + 4] = uncap + 0.5f * (1.0f - bal);
  }
}

// ============================================================
// FALLBACK kernels (only used if ws too small)
// ============================================================
__global__ __launch_bounds__(128) void topk_fb_kernel(
    const float* __restrict__ h, float* __restrict__ out,
    float* __restrict__ epart, int* __restrict__ cnt,
    int* __restrict__ lists, float* __restrict__ sc)
{
#pragma clang fp contract(off)
  const int n = blockIdx.x;
  const int t = threadIdx.x;
  __shared__ float sE[M_EXP];
  __shared__ int   sIdx[K_SEL];
  const float4* hp = (const float4*)(h + (size_t)n * (M_EXP * B_DIM) + t * B_DIM);
  float r0=0.f,r1=0.f,r2=0.f,r3=0.f,r4=0.f,r5=0.f,r6=0.f,r7=0.f;
#pragma unroll
  for (int f = 0; f < 16; f += 2) {
    float4 a = hp[f];
    float4 b = hp[f + 1];
    r0 += a.x * a.x;  r1 += a.y * a.y;  r2 += a.z * a.z;  r3 += a.w * a.w;
    r4 += b.x * b.x;  r5 += b.y * b.y;  r6 += b.z * b.z;  r7 += b.w * b.w;
  }
  const float e = ((r0 + r1) + (r2 + r3)) + ((r4 + r5) + (r6 + r7));
  sE[t] = e;
  atomicAdd(&epart[(n & 63) * M_EXP + t], e);
  __syncthreads();
  if (t < 64) {
    float ea = sE[t], eb = sE[t + 64], capt = 0.f;
#pragma unroll
    for (int j = 0; j < K_SEL; ++j) {
      float v; int idx;
      if (eb > ea) { v = eb; idx = t + 64; } else { v = ea; idx = t; }
#pragma unroll
      for (int off = 32; off >= 1; off >>= 1) {
        float ov = __shfl_xor(v, off);
        int   oi = __shfl_xor(idx, off);
        if (ov > v || (ov == v && oi < idx)) { v = ov; idx = oi; }
      }
      if (t == 0) sIdx[j] = idx;
      if (idx == t)      ea = -3.402823466e38f;
      if (idx == t + 64) eb = -3.402823466e38f;
      capt += v;
    }
    if (t == 0) atomicAdd(&sc[0], capt);
  }
  __syncthreads();
  if (t < K_SEL) {
    int ii = sIdx[t];
    out[IDX_OFF + n * K_SEL + t] = (float)ii;
    int pos = atomicAdd(&cnt[ii], 1);
    lists[ii * N_ROWS + pos] = (n << 3) | t;
  }
  {
    int j = t >> 4, c4 = t & 15;
    int src = sIdx[j];
    const float4* gp = (const float4*)(h + (size_t)n * (M_EXP * B_DIM) + src * B_DIM);
    float4 v = gp[c4];
    ((float4*)(out + (size_t)n * (K_SEL * B_DIM) + j * B_DIM))[c4] = v;
  }
}

__global__ __launch_bounds__(128) void xhat_kernel(
    const float* __restrict__ V, const float* __restrict__ out,
    const int* __restrict__ cnt, const int* __restrict__ lists,
    float* __restrict__ xhat)
{
  const int t  = threadIdx.x;
  const int d0 = blockIdx.x * 128;
  const int ex = blockIdx.y;
  const int ybase = blockIdx.z * 512;
  const int c = cnt[ex];
  if (ybase >= c) return;
  const int rowsChunk = min(512, c - ybase);
  __shared__ float Vt[64 * 132];
  __shared__ float hvT[64 * 68];
  __shared__ int   nbuf[64];
  {
    const float4* vp = (const float4*)(V + (size_t)(d0 + t) * (M_EXP * B_DIM) + ex * B_DIM);
    const int colt = t + ((t >> 6) << 2);
#pragma unroll
    for (int f = 0; f < 16; ++f) {
      float4 vv = vp[f];
      int b = f * 4;
      Vt[(b + 0) * 132 + colt] = vv.x;
      Vt[(b + 1) * 132 + colt] = vv.y;
      Vt[(b + 2) * 132 + colt] = vv.z;
      Vt[(b + 3) * 132 + colt] = vv.w;
    }
  }
  const int rg = t >> 4, dg = t & 15;
  const int hvBase = rg * 8;
  const int vBase  = dg * 8 + ((dg >> 3) << 2);
  for (int it = 0; it * 64 < rowsChunk; ++it) {
    const int rows = min(64, rowsChunk - it * 64);
    {
      const int r = t >> 1, half = t & 1;
      if (r < rows) {
        int q = lists[ex * N_ROWS + ybase + it * 64 + r];
        int nn = q >> 3, jj = q & 7;
        if (half == 0) nbuf[r] = nn;
        const float4* hp = (const float4*)(out + ((size_t)nn * K_SEL + jj) * B_DIM + half * 32);
#pragma unroll
        for (int f = 0; f < 8; ++f) {
          float4 hv = hp[f];
          int b = half * 32 + f * 4;
          hvT[(b + 0) * 68 + r] = hv.x;
          hvT[(b + 1) * 68 + r] = hv.y;
          hvT[(b + 2) * 68 + r] = hv.z;
          hvT[(b + 3) * 68 + r] = hv.w;
        }
      } else {
        if (half == 0) nbuf[r] = 0;
#pragma unroll
        for (int f = 0; f < 8; ++f) {
          int b = half * 32 + f * 4;
          hvT[(b + 0) * 68 + r] = 0.f;
          hvT[(b + 1) * 68 + r] = 0.f;
          hvT[(b + 2) * 68 + r] = 0.f;
          hvT[(b + 3) * 68 + r] = 0.f;
        }
      }
    }
    __syncthreads();
    float acc[8][8];
#pragma unroll
    for (int a = 0; a < 8; ++a)
#pragma unroll
      for (int d = 0; d < 8; ++d) acc[a][d] = 0.f;
#pragma unroll 4
    for (int b = 0; b < 64; ++b) {
      float4 h0 = *(const float4*)&hvT[b * 68 + hvBase];
      float4 h1 = *(const float4*)&hvT[b * 68 + hvBase + 4];
      float4 v0 = *(const float4*)&Vt[b * 132 + vBase];
      float4 v1 = *(const float4*)&Vt[b * 132 + vBase + 4];
      float hv[8] = {h0.x, h0.y, h0.z, h0.w, h1.x, h1.y, h1.z, h1.w};
      float vv[8] = {v0.x, v0.y, v0.z, v0.w, v1.x, v1.y, v1.z, v1.w};
#pragma unroll
      for (int a = 0; a < 8; ++a)
#pragma unroll
        for (int d = 0; d < 8; ++d)
          acc[a][d] = fmaf(hv[a], vv[d], acc[a][d]);
    }
#pragma unroll
    for (int a = 0; a < 8; ++a) {
      int r2 = rg * 8 + a;
      if (r2 < rows) {
        float* xp = xhat + (size_t)nbuf[r2] * D_DIM + d0 + dg * 8;
#pragma unroll
        for (int d = 0; d < 8; ++d) atomicAdd(xp + d, acc[a][d]);
      }
    }
    __syncthreads();
  }
}

__global__ __launch_bounds__(256) void reduce_kernel(
    const float* __restrict__ x, const float* __restrict__ xhat,
    float* __restrict__ sc)
{
  const size_t total4 = (size_t)N_ROWS * D_DIM / 4;
  const float4* x4  = (const float4*)x;
  const float4* xh4 = (const float4*)xhat;
  float recon = 0.f, uncap = 0.f;
  for (size_t i = (size_t)blockIdx.x * 256 + threadIdx.x; i < total4; i += (size_t)1024 * 256) {
    float4 a = x4[i], b = xh4[i];
    recon += b.x * b.x + b.y * b.y + b.z * b.z + b.w * b.w;
    float dx = a.x - b.x, dy = a.y - b.y, dz = a.z - b.z, dw = a.w - b.w;
    uncap += dx * dx + dy * dy + dz * dz + dw * dw;
  }
#pragma unroll
  for (int off = 32; off >= 1; off >>= 1) {
    recon += __shfl_down(recon, off);
    uncap += __shfl_down(uncap, off);
  }
  __shared__ float sR[4], sU[4];
  int wid = threadIdx.x >> 6, lane = threadIdx.x & 63;
  if (lane == 0) { sR[wid] = recon; sU[wid] = uncap; }
  __syncthreads();
  if (threadIdx.x == 0) {
    atomicAdd(&sc[1], sR[0] + sR[1] + sR[2] + sR[3]);
    atomicAdd(&sc[2], sU[0] + sU[1] + sU[2] + sU[3]);
  }
}

__global__ __launch_bounds__(128) void finalize_fb_kernel(
    const float* __restrict__ epart, const float* __restrict__ sc,
    float* __restrict__ out)
{
  const int t = threadIdx.x;
  __shared__ float sAvg[M_EXP];
  float s = 0.f;
  for (int c2 = 0; c2 < 64; ++c2) s += epart[c2 * M_EXP + t];
  sAvg[t] = s / (float)N_ROWS;
  __syncthreads();
  if (t == 0) {
    float denom = 0.f;
    for (int i = 0; i < M_EXP; ++i) denom += sAvg[i];
    if (denom < 1e-8f) denom = 1e-8f;
    float ent = 0.f;
    for (int i = 0; i < M_EXP; ++i) {
      float p = sAvg[i] / denom;
      if (p < 1e-8f) p = 1e-8f;
      ent += p * logf(p);
    }
    float bal   = -ent / logf(128.0f);
    float capt  = sc[0] / (float)N_ROWS;
    float recon = sc[1] / (float)N_ROWS;
    float uncap = sc[2] / (float)N_ROWS;
    out[SC_OFF + 0] = capt;
    out[SC_OFF + 1] = recon;
    out[SC_OFF + 2] = uncap;
    out[SC_OFF + 3] = bal;
    out[SC_OFF + 4] = uncap + 0.5f * (1.0f - bal);
  }
}

extern "C" void kernel_launch(void* const* d_in, const int* in_sizes, int n_in,
                              void* d_out, int out_size, void* d_ws, size_t ws_size,
                              hipStream_t stream) {
  const float* x = (const float*)d_in[0];
  const float* h = (const float*)d_in[1];
  const float* V = (const float*)d_in[2];
  float* out = (float*)d_out;
  char* ws = (char*)d_ws;

  if (ws_size >= F_NEED) {
    float* epart = (float*)(ws + F_EPART);
    int*   cnt   = (int*)(ws + F_CNT);
    int*   lists = (int*)(ws + F_LISTS);
    uint2* hsb   = (uint2*)(ws + F_HSB);
    uint4* Vb    = (uint4*)(ws + F_VB);
    uint4* y     = (uint4*)(ws + F_Y);
    float* capt_part  = (float*)(ws + F_CAPT);
    float* recon_part = (float*)(ws + F_RECON);
    float* uncap_part = (float*)(ws + F_UNCAP);

    zero_kernel<<<64, 256, 0, stream>>>((float*)ws);
    topk_kernel<<<4096, 256, 0, stream>>>(h, V, out, epart, cnt, lists, capt_part, hsb, Vb);
    b1_kernel<<<dim3(8, 128), 256, 0, stream>>>(Vb, (const uint4*)hsb, cnt, lists, y);
    b2_kernel<<<4096, 256, 0, stream>>>(x, y, recon_part, uncap_part);
    finalize_kernel<<<1, 128, 0, stream>>>(epart, capt_part, recon_part, uncap_part, out);
  } else {
    float* xhat  = (float*)(ws + WS_XHAT);
    float* epart = (float*)(ws + WS_EPART);
    int*   cnt   = (int*)(ws + WS_CNT);
    float* sc    = (float*)(ws + WS_SC);
    int*   lists = (int*)(ws + WS_LISTS);

    hipMemsetAsync(d_ws, 0, WS_ZERO_BYTES, stream);
    topk_fb_kernel<<<N_ROWS, 128, 0, stream>>>(h, out, epart, cnt, lists, sc);
    xhat_kernel<<<dim3(8, 128, 16), 128, 0, stream>>>(V, out, cnt, lists, xhat);
    reduce_kernel<<<1024, 256, 0, stream>>>(x, xhat, sc);
    finalize_fb_kernel<<<1, 128, 0, stream>>>(epart, sc, out);
  }
}